// Round 10
// baseline (412.134 us; speedup 1.0000x reference)
//
#include <hip/hip_runtime.h>
#include <hip/hip_bf16.h>

#define PI_F 3.14159265358979323846f

typedef short  bf16x8 __attribute__((ext_vector_type(8)));
typedef unsigned short u16x8 __attribute__((ext_vector_type(8)));
typedef float  f32x4  __attribute__((ext_vector_type(4)));
typedef float  f32x4u __attribute__((ext_vector_type(4), aligned(4)));

// ---- ws layout (bytes) ----
#define OUT3_OFF  0                       // [3][1024][257] f32 = 3,158,016 B
#define TPACK_OFF 3158016                 // [512 tiles][64][8] bf16 = 524,288 B (U then V)

#define RPB 8                             // rows per block in mlp_kernel

static __device__ __forceinline__ unsigned short f2bf(float x) {
    unsigned int u = __float_as_uint(x);
    unsigned int r = (u + 0x7fffu + ((u >> 16) & 1u)) >> 16;   // RNE
    return (unsigned short)r;
}

// ------------------------------------------------------------------
// Kernel A: three LinearOutputStacks. 8 rows/block, grid (128,3).
// ------------------------------------------------------------------

__device__ __forceinline__ void block_ln8(float (*buf)[256], float* mrow, float* rrow)
{
    const int tid = threadIdx.x;
    const int lane = tid & 63, wv = tid >> 6;
    for (int r = wv; r < RPB; r += 4) {
        float s = 0.f, s2 = 0.f;
        #pragma unroll
        for (int j = 0; j < 4; j++) {
            float v = buf[r][lane + 64*j];
            s += v; s2 += v*v;
        }
        #pragma unroll
        for (int o = 32; o > 0; o >>= 1) {
            s  += __shfl_xor(s,  o, 64);
            s2 += __shfl_xor(s2, o, 64);
        }
        if (lane == 0) {
            float m   = s * (1.f/256.f);
            float var = s2 * (1.f/256.f) - m*m;
            mrow[r] = m;
            rrow[r] = rsqrtf(var + 1e-5f);
        }
    }
    __syncthreads();
    #pragma unroll
    for (int r = 0; r < RPB; r++)
        buf[r][tid] = (buf[r][tid] - mrow[r]) * rrow[r];
    __syncthreads();
}

// KDIM -> 256 matmul + bias + leaky_relu(0.2)
template<int KDIM>
__device__ __forceinline__ void mmv(const float (*in)[KDIM == 128 ? 128 : 256],
                                    const float* __restrict__ W, int wstride,
                                    const float* __restrict__ bias, float (*outb)[256])
{
    const int tid = threadIdx.x;
    float acc[RPB];
    #pragma unroll
    for (int r = 0; r < RPB; r++) acc[r] = 0.f;
    const float* Wp = W + tid;
    for (int l16 = 0; l16 < KDIM; l16 += 16) {
        float wbuf[16];
        #pragma unroll
        for (int j = 0; j < 16; j++) wbuf[j] = Wp[(size_t)(l16 + j)*wstride];
        #pragma unroll
        for (int q = 0; q < 4; q++) {
            f32x4 iq[RPB];
            #pragma unroll
            for (int r = 0; r < RPB; r++) iq[r] = *(const f32x4*)&in[r][l16 + q*4];
            #pragma unroll
            for (int jj = 0; jj < 4; jj++)
                #pragma unroll
                for (int r = 0; r < RPB; r++)
                    acc[r] = fmaf(iq[r][jj], wbuf[q*4 + jj], acc[r]);
        }
    }
    const float bb = bias[tid];
    #pragma unroll
    for (int r = 0; r < RPB; r++) {
        float v = acc[r] + bb;
        outb[r][tid] = (v >= 0.f) ? v : 0.2f*v;
    }
}

__global__ __launch_bounds__(256) void mlp_kernel(
    const float* __restrict__ latents,
    const float* __restrict__ Win,  const float* __restrict__ b_in,
    const float* __restrict__ Wh,   const float* __restrict__ b_h,
    const float* __restrict__ Wout, const float* __restrict__ b_out,
    float* __restrict__ out3)
{
    __shared__ float bufA[RPB][128];
    __shared__ float bufB[RPB][256];
    __shared__ float bufC[RPB][256];
    __shared__ float mrow[RPB], rrow[RPB];

    const int tid  = threadIdx.x;
    const int s    = blockIdx.y;
    const int row0 = blockIdx.x * RPB;

    for (int idx = tid; idx < RPB*128; idx += 256) {
        int r = idx >> 7, l = idx & 127;
        bufA[r][l] = latents[(size_t)(row0 + r)*128 + l];
    }
    __syncthreads();

    mmv<128>(bufA, Win + (size_t)s*128*256, 256, b_in + s*256, bufB);
    __syncthreads();
    block_ln8(bufB, mrow, rrow);

    mmv<256>(bufB, Wh + ((size_t)s*2 + 0)*256*256, 256, b_h + (s*2 + 0)*256, bufC);
    __syncthreads();
    block_ln8(bufC, mrow, rrow);

    mmv<256>(bufC, Wh + ((size_t)s*2 + 1)*256*256, 256, b_h + (s*2 + 1)*256, bufB);
    __syncthreads();
    block_ln8(bufB, mrow, rrow);

    // output layer: 256 -> 257 (+bias), raw
    for (int pass = 0; pass < 2; ++pass) {
        int n = tid + pass*256;
        if (n < 257) {
            float acc[RPB];
            #pragma unroll
            for (int r = 0; r < RPB; r++) acc[r] = 0.f;
            const float* Wp = Wout + (size_t)s*256*257 + n;
            for (int l16 = 0; l16 < 256; l16 += 16) {
                float wbuf[16];
                #pragma unroll
                for (int j = 0; j < 16; j++) wbuf[j] = Wp[(size_t)(l16 + j)*257];
                #pragma unroll
                for (int q = 0; q < 4; q++) {
                    f32x4 iq[RPB];
                    #pragma unroll
                    for (int r = 0; r < RPB; r++) iq[r] = *(const f32x4*)&bufB[r][l16 + q*4];
                    #pragma unroll
                    for (int jj = 0; jj < 4; jj++)
                        #pragma unroll
                        for (int r = 0; r < RPB; r++)
                            acc[r] = fmaf(iq[r][jj], wbuf[q*4 + jj], acc[r]);
                }
            }
            float bb = b_out[s*257 + n];
            for (int r = 0; r < RPB; r++)
                out3[((size_t)s*1024 + row0 + r)*257 + n] = acc[r] + bb;
        }
    }
}

// ------------------------------------------------------------------
// K1: pack windowed iDFT bases, MFMA B-fragment order, K=512, N=256.
//  U[k2][w] = hann[w]       * T[k2][w]
//  V[k2][w] = hann[w+256] * (-1)^k * T[k2][w]     (k = k2>>1)
// where T[2k][w]=cos(2pi k w/512), T[2k+1][w]=sin(2pi k w/512).
// tiles 0..255 = U, 256..511 = V.
// ------------------------------------------------------------------
__global__ __launch_bounds__(256) void tpack_init(unsigned short* __restrict__ tp)
{
    int g = blockIdx.x * 256 + threadIdx.x;      // 512*64 = 32768 threads exactly
    int tile = g >> 6, l = g & 63;
    int half = tile >> 8;                        // 0 = U, 1 = V
    int tl = tile & 255;
    int ks = tl >> 4, nt = tl & 15;
    u16x8 v;
    #pragma unroll
    for (int j = 0; j < 8; ++j) {
        int k2 = ks*32 + ((l >> 4) << 3) + j;    // < 512
        int w  = nt*16 + (l & 15);               // < 256
        int kk = k2 >> 1;
        int m  = (kk * w) & 511;                 // exact angle reduction
        float ang = (float)m * (PI_F / 256.f);
        float sn, cn; sincosf(ang, &sn, &cn);
        float base = (k2 & 1) ? sn : cn;
        float cw = cosf((float)w * (PI_F / 256.f));
        float val;
        if (half == 0) {
            val = (0.5f - 0.5f*cw) * base;                       // hann[w]
        } else {
            val = (0.5f + 0.5f*cw) * ((kk & 1) ? -base : base);  // hann[w+256]*(-1)^k
        }
        v[j] = f2bf(val);
    }
    *(u16x8*)(tp + (size_t)g * 8) = v;
}

// ------------------------------------------------------------------
// K2: full-row fused scan + windowed-GEMM (Hann/OLA folded into B tables).
// grid 1024, block 512 (8 waves), 2 blocks/CU.
//   out[t][j] = sum_k AB_t[k]*U[k][j] + AB_{t-1}[k]*V[k][j]
//               + (-1)^j * (h1[j]*a256[t] + h2[j]*a256[t-1])
// abt[65][260]: row 1+f = frame F0+f; row 0 = frame F0-1 (boundary; zeros
// for sweep 0, copied from row 64 between sweeps). acc = 32 AGPR only.
// ------------------------------------------------------------------
__global__ __launch_bounds__(512, 4) void synth_row(
    const float* __restrict__ out3,
    const float* __restrict__ phase0_u,
    const float* __restrict__ noise_u,
    const unsigned short* __restrict__ tpack,
    float* __restrict__ out)
{
    __shared__ __align__(16) unsigned int abt[65*260];   // 67,600 B
    __shared__ float a256s[65];
    __shared__ float stash_pr[257];
    __shared__ float stash_mag[257];
    __shared__ __align__(16) float nbuf[8][260];

    const int tid = threadIdx.x;
    const int row = blockIdx.x;
    const int b   = row >> 9;
    const int e   = row & 511;

    const float inv = 0.04419417382415922f;              // 1/sqrt(512)

    // ---- init persistent stash + boundary row ----
    if (tid <= 256) {
        stash_pr[tid]  = phase0_u[(size_t)row*257 + tid] - 0.5f;   // revolutions
        stash_mag[tid] = out3[((size_t)0*1024 + row)*257 + tid];   // initial
    }
    if (tid < 260) abt[tid] = 0;                          // frame F0-1 = 0
    if (tid == 260) a256s[0] = 0.f;

    const float* nrow = noise_u + ((size_t)b*128*512 + e)*257;
    const size_t nstride = (size_t)512*257;

    const int l  = tid & 63;
    const int wv = tid >> 6;                              // 0..7
    const int m0 = l & 15;
    const int ac = l >> 4;
    const int j0 = wv*32 + m0;                            // output col (nt=0)
    float h1_0, h2_0, h1_1, h2_1;
    {
        float c0 = __builtin_amdgcn_cosf((float)j0 * (1.f/512.f));
        h1_0 = 0.5f - 0.5f*c0;  h2_0 = 0.5f + 0.5f*c0;
        float c1 = __builtin_amdgcn_cosf((float)(j0 + 16) * (1.f/512.f));
        h1_1 = 0.5f - 0.5f*c1;  h2_1 = 0.5f + 0.5f*c1;
    }
    const float psgn = (m0 & 1) ? -1.f : 1.f;             // (-1)^j

    const int4* abt4 = (const int4*)abt;                  // row stride 65 int4
    const int4* Tp   = (const int4*)tpack;

    __syncthreads();

    for (int sweep = 0; sweep < 2; ++sweep) {
        const int F0 = sweep * 64;

        // ---- phase 1: scan 64 frames -> abt rows 1..64 (+ a256s[1..64]) ----
        {
            float res = 0.f, dith = 0.f, gd = 0.f, cs = 0.f, pr = 0.f, mag = 0.f;
            if (tid <= 256) {
                const int k = tid;
                float rpre = out3[((size_t)1*1024 + row)*257 + k];
                float dpre = out3[((size_t)2*1024 + row)*257 + k];
                res  = 0.5f + 0.4995f / (1.f + expf(-rpre));
                dith = 1.f / (1.f + expf(-dpre));
                gd   = (float)k * (1.f/512.f);
                cs   = ((k == 0) | (k == 256) ? 1.f : 2.f) * inv;
                pr   = stash_pr[k];
                mag  = stash_mag[k];
            }

            for (int grp = 0; grp < 8; ++grp) {
                {   // cooperative load: wave wv loads frame F0+grp*8+wv
                    const int t = F0 + grp*8 + wv;
                    const float* pf = nrow + (size_t)t*nstride;
                    f32x4u v = __builtin_nontemporal_load(((const f32x4u*)pf) + l);
                    *(f32x4u*)&nbuf[wv][l*4] = v;
                    if (tid < 8) {
                        const int t2 = F0 + grp*8 + tid;
                        nbuf[tid][256] = __builtin_nontemporal_load(
                                             &nrow[(size_t)t2*nstride + 256]);
                    }
                }
                __syncthreads();

                if (tid <= 256) {
                    const int k = tid;
                    #pragma unroll
                    for (int j = 0; j < 8; ++j) {
                        int t = F0 + grp*8 + j;
                        if (t >= 1) {
                            float nz = nbuf[j][k];
                            mag *= res;
                            pr  += gd + dith * (nz - 0.5f);
                        }
                        float fr = pr - floorf(pr);
                        float sn = __builtin_amdgcn_sinf(fr);
                        float cn = __builtin_amdgcn_cosf(fr);
                        float am = cs * mag;
                        if (k < 256) {
                            abt[(1 + grp*8 + j)*260 + k] =
                                (unsigned int)f2bf(am*cn) | ((unsigned int)f2bf(-am*sn) << 16);
                        } else {
                            a256s[1 + grp*8 + j] = am * cn;   // Nyquist: cos only
                        }
                    }
                }
                __syncthreads();   // abt/nbuf consumed before next grp / GEMM
            }
            if (tid <= 256) {
                stash_pr[tid]  = pr;
                stash_mag[tid] = mag;
            }
        }

        // ---- phase 2: GEMM  out-frames = AB_t*U + AB_{t-1}*V ----
        f32x4 acc[4][2];
        #pragma unroll
        for (int mt = 0; mt < 4; ++mt) {
            acc[mt][0] = (f32x4){0.f, 0.f, 0.f, 0.f};
            acc[mt][1] = (f32x4){0.f, 0.f, 0.f, 0.f};
        }

        for (int ks = 0; ks < 16; ++ks) {
            const int4* tu = Tp + (size_t)((ks*16 + wv*2) << 6) + l;
            int4 u0 = tu[0];
            int4 u1 = tu[64];
            int4 v0 = tu[256*64];
            int4 v1 = tu[256*64 + 64];
            bf16x8 BU0 = *(bf16x8*)&u0;
            bf16x8 BU1 = *(bf16x8*)&u1;
            bf16x8 BV0 = *(bf16x8*)&v0;
            bf16x8 BV1 = *(bf16x8*)&v1;
            #pragma unroll
            for (int mt = 0; mt < 4; ++mt) {
                int4 au = abt4[(1 + m0 + 16*mt)*65 + ks*4 + ac];   // frame t
                int4 av = abt4[(    m0 + 16*mt)*65 + ks*4 + ac];   // frame t-1
                bf16x8 AU = *(bf16x8*)&au;
                bf16x8 AV = *(bf16x8*)&av;
                acc[mt][0] = __builtin_amdgcn_mfma_f32_16x16x32_bf16(AU, BU0, acc[mt][0], 0, 0, 0);
                acc[mt][0] = __builtin_amdgcn_mfma_f32_16x16x32_bf16(AV, BV0, acc[mt][0], 0, 0, 0);
                acc[mt][1] = __builtin_amdgcn_mfma_f32_16x16x32_bf16(AU, BU1, acc[mt][1], 0, 0, 0);
                acc[mt][1] = __builtin_amdgcn_mfma_f32_16x16x32_bf16(AV, BV1, acc[mt][1], 0, 0, 0);
            }
        }

        // ---- phase 3: direct epilogue stores (Nyquist add) ----
        #pragma unroll
        for (int mt = 0; mt < 4; ++mt) {
            #pragma unroll
            for (int r = 0; r < 4; ++r) {
                int t_loc = mt*16 + ac*4 + r;
                float sc = a256s[t_loc + 1];      // a256[t]
                float sp = a256s[t_loc];          // a256[t-1]
                float add0 = psgn * (h1_0*sc + h2_0*sp);
                float add1 = psgn * (h1_1*sc + h2_1*sp);
                float* o = out + (size_t)row*32768 + (size_t)(F0 + t_loc)*256;
                __builtin_nontemporal_store(acc[mt][0][r] + add0, o + j0);
                __builtin_nontemporal_store(acc[mt][1][r] + add1, o + j0 + 16);
            }
        }
        __syncthreads();   // abt + a256s reads done

        // ---- boundary copy for next sweep ----
        if (sweep == 0) {
            if (tid < 260) abt[tid] = abt[64*260 + tid];
            if (tid == 260) a256s[0] = a256s[64];
        }
        // next sweep's scan barriers order these writes vs. reads
    }
}

// ------------------------------------------------------------------

extern "C" void kernel_launch(void* const* d_in, const int* in_sizes, int n_in,
                              void* d_out, int out_size, void* d_ws, size_t ws_size,
                              hipStream_t stream)
{
    const float* latents  = (const float*)d_in[0];
    const float* phase0_u = (const float*)d_in[1];
    const float* noise_u  = (const float*)d_in[2];
    const float* Win      = (const float*)d_in[3];
    const float* b_in     = (const float*)d_in[4];
    const float* Wh       = (const float*)d_in[5];
    const float* b_h      = (const float*)d_in[6];
    const float* Wout     = (const float*)d_in[7];
    const float* b_out    = (const float*)d_in[8];

    unsigned char* ws = (unsigned char*)d_ws;
    float*          out3  = (float*)(ws + OUT3_OFF);
    unsigned short* tpack = (unsigned short*)(ws + TPACK_OFF);
    float*          out   = (float*)d_out;

    dim3 gA(128, 3);
    mlp_kernel<<<gA, 256, 0, stream>>>(latents, Win, b_in, Wh, b_h, Wout, b_out, out3);
    tpack_init<<<128, 256, 0, stream>>>(tpack);
    synth_row<<<1024, 512, 0, stream>>>(out3, phase0_u, noise_u, tpack, out);
}

// Round 11
// 331.264 us; speedup vs baseline: 1.2441x; 1.2441x over previous
//
#include <hip/hip_runtime.h>
#include <hip/hip_bf16.h>

#define PI_F 3.14159265358979323846f

typedef short  bf16x8 __attribute__((ext_vector_type(8)));
typedef unsigned short u16x8 __attribute__((ext_vector_type(8)));
typedef float  f32x4  __attribute__((ext_vector_type(4)));
typedef float  f32x4u __attribute__((ext_vector_type(4), aligned(4)));

// ---- ws layout (bytes) ----
#define OUT3_OFF  0                       // [3][1024][257] f32 = 3,158,016 B
#define TPACK_OFF 3158016                 // [256 tiles][64][8] bf16 = 262,144 B

#define RPB 8                             // rows per block in mlp_kernel

static __device__ __forceinline__ unsigned short f2bf(float x) {
    unsigned int u = __float_as_uint(x);
    unsigned int r = (u + 0x7fffu + ((u >> 16) & 1u)) >> 16;   // RNE
    return (unsigned short)r;
}

// ------------------------------------------------------------------
// Kernel A: three LinearOutputStacks. 8 rows/block, grid (128,3).
// ------------------------------------------------------------------

__device__ __forceinline__ void block_ln8(float (*buf)[256], float* mrow, float* rrow)
{
    const int tid = threadIdx.x;
    const int lane = tid & 63, wv = tid >> 6;
    for (int r = wv; r < RPB; r += 4) {
        float s = 0.f, s2 = 0.f;
        #pragma unroll
        for (int j = 0; j < 4; j++) {
            float v = buf[r][lane + 64*j];
            s += v; s2 += v*v;
        }
        #pragma unroll
        for (int o = 32; o > 0; o >>= 1) {
            s  += __shfl_xor(s,  o, 64);
            s2 += __shfl_xor(s2, o, 64);
        }
        if (lane == 0) {
            float m   = s * (1.f/256.f);
            float var = s2 * (1.f/256.f) - m*m;
            mrow[r] = m;
            rrow[r] = rsqrtf(var + 1e-5f);
        }
    }
    __syncthreads();
    #pragma unroll
    for (int r = 0; r < RPB; r++)
        buf[r][tid] = (buf[r][tid] - mrow[r]) * rrow[r];
    __syncthreads();
}

// KDIM -> 256 matmul + bias + leaky_relu(0.2)
template<int KDIM>
__device__ __forceinline__ void mmv(const float (*in)[KDIM == 128 ? 128 : 256],
                                    const float* __restrict__ W, int wstride,
                                    const float* __restrict__ bias, float (*outb)[256])
{
    const int tid = threadIdx.x;
    float acc[RPB];
    #pragma unroll
    for (int r = 0; r < RPB; r++) acc[r] = 0.f;
    const float* Wp = W + tid;
    for (int l16 = 0; l16 < KDIM; l16 += 16) {
        float wbuf[16];
        #pragma unroll
        for (int j = 0; j < 16; j++) wbuf[j] = Wp[(size_t)(l16 + j)*wstride];
        #pragma unroll
        for (int q = 0; q < 4; q++) {
            f32x4 iq[RPB];
            #pragma unroll
            for (int r = 0; r < RPB; r++) iq[r] = *(const f32x4*)&in[r][l16 + q*4];
            #pragma unroll
            for (int jj = 0; jj < 4; jj++)
                #pragma unroll
                for (int r = 0; r < RPB; r++)
                    acc[r] = fmaf(iq[r][jj], wbuf[q*4 + jj], acc[r]);
        }
    }
    const float bb = bias[tid];
    #pragma unroll
    for (int r = 0; r < RPB; r++) {
        float v = acc[r] + bb;
        outb[r][tid] = (v >= 0.f) ? v : 0.2f*v;
    }
}

__global__ __launch_bounds__(256) void mlp_kernel(
    const float* __restrict__ latents,
    const float* __restrict__ Win,  const float* __restrict__ b_in,
    const float* __restrict__ Wh,   const float* __restrict__ b_h,
    const float* __restrict__ Wout, const float* __restrict__ b_out,
    float* __restrict__ out3)
{
    __shared__ float bufA[RPB][128];
    __shared__ float bufB[RPB][256];
    __shared__ float bufC[RPB][256];
    __shared__ float mrow[RPB], rrow[RPB];

    const int tid  = threadIdx.x;
    const int s    = blockIdx.y;
    const int row0 = blockIdx.x * RPB;

    for (int idx = tid; idx < RPB*128; idx += 256) {
        int r = idx >> 7, l = idx & 127;
        bufA[r][l] = latents[(size_t)(row0 + r)*128 + l];
    }
    __syncthreads();

    mmv<128>(bufA, Win + (size_t)s*128*256, 256, b_in + s*256, bufB);
    __syncthreads();
    block_ln8(bufB, mrow, rrow);

    mmv<256>(bufB, Wh + ((size_t)s*2 + 0)*256*256, 256, b_h + (s*2 + 0)*256, bufC);
    __syncthreads();
    block_ln8(bufC, mrow, rrow);

    mmv<256>(bufC, Wh + ((size_t)s*2 + 1)*256*256, 256, b_h + (s*2 + 1)*256, bufB);
    __syncthreads();
    block_ln8(bufB, mrow, rrow);

    // output layer: 256 -> 257 (+bias), raw
    for (int pass = 0; pass < 2; ++pass) {
        int n = tid + pass*256;
        if (n < 257) {
            float acc[RPB];
            #pragma unroll
            for (int r = 0; r < RPB; r++) acc[r] = 0.f;
            const float* Wp = Wout + (size_t)s*256*257 + n;
            for (int l16 = 0; l16 < 256; l16 += 16) {
                float wbuf[16];
                #pragma unroll
                for (int j = 0; j < 16; j++) wbuf[j] = Wp[(size_t)(l16 + j)*257];
                #pragma unroll
                for (int q = 0; q < 4; q++) {
                    f32x4 iq[RPB];
                    #pragma unroll
                    for (int r = 0; r < RPB; r++) iq[r] = *(const f32x4*)&bufB[r][l16 + q*4];
                    #pragma unroll
                    for (int jj = 0; jj < 4; jj++)
                        #pragma unroll
                        for (int r = 0; r < RPB; r++)
                            acc[r] = fmaf(iq[r][jj], wbuf[q*4 + jj], acc[r]);
                }
            }
            float bb = b_out[s*257 + n];
            for (int r = 0; r < RPB; r++)
                out3[((size_t)s*1024 + row0 + r)*257 + n] = acc[r] + bb;
        }
    }
}

// ------------------------------------------------------------------
// K1: pack iDFT basis T[k2][w] (bf16), MFMA B-fragment order.
// Only w = 0..255 columns (w-symmetry handled in GEMM): 256 tiles, 256 KB.
// ------------------------------------------------------------------
__global__ __launch_bounds__(256) void tpack_init(unsigned short* __restrict__ tp)
{
    int g = blockIdx.x * 256 + threadIdx.x;      // 256*64 = 16384 threads exactly
    int tile = g >> 6, l = g & 63;
    int ks = tile >> 4, nt = tile & 15;
    u16x8 v;
    #pragma unroll
    for (int j = 0; j < 8; ++j) {
        int k2 = ks*32 + ((l >> 4) << 3) + j;    // < 512
        int w  = nt*16 + (l & 15);               // < 256
        int kk = k2 >> 1;
        int m  = (kk * w) & 511;                 // exact angle reduction
        float ang = (float)m * (PI_F / 256.f);
        float sn, cn; sincosf(ang, &sn, &cn);
        v[j] = f2bf((k2 & 1) ? sn : cn);
    }
    *(u16x8*)(tp + (size_t)g * 8) = v;
}

// ------------------------------------------------------------------
// K2: full-row fused scan + MFMA iDFT + Hann/OLA.
// grid 1024 (one block per row), block 256 (4 waves),
// __launch_bounds__(256,2): 2 waves/EU -> 2 blocks/CU @ 256-VGPR budget.
// No register cap pressure: accL/accR = 128 f32 + working set < 256.
// Thread tid owns bin k=tid for the scan (thread 255 also owns k=256),
// and output cols (wv*64 + nt*16 + m0) / +256 for the GEMM.
// LDS: abt u32[64][260] (scan/GEMM)  U  xbf f32[32][516] (epilogue),
//      nbuf[8][260] noise staging, a256s[64].  Total 73.4 KB.
// ------------------------------------------------------------------
__global__ __launch_bounds__(256, 2) void synth_row(
    const float* __restrict__ out3,
    const float* __restrict__ phase0_u,
    const float* __restrict__ noise_u,
    const unsigned short* __restrict__ tpack,
    float* __restrict__ out)
{
    __shared__ __align__(16) unsigned char lds_raw[66560];
    __shared__ __align__(16) float nbuf[8][260];
    __shared__ float a256s[64];
    unsigned int* abt = (unsigned int*)lds_raw;     // [64][260] u32
    float*        xbf = (float*)lds_raw;            // [32][516] f32

    const int tid = threadIdx.x;
    const int row = blockIdx.x;
    const int b   = row >> 9;
    const int e   = row & 511;

    const float inv = 0.04419417382415922f;         // 1/sqrt(512)

    // ---- per-thread sequential state (k = tid), in revolutions ----
    const int k = tid;
    float res, dith, pr, mag, gd, cs;
    {
        float ini  = out3[((size_t)0*1024 + row)*257 + k];
        float rpre = out3[((size_t)1*1024 + row)*257 + k];
        float dpre = out3[((size_t)2*1024 + row)*257 + k];
        res  = 0.5f + 0.4995f / (1.f + expf(-rpre));
        dith = 1.f / (1.f + expf(-dpre));
        pr   = phase0_u[(size_t)row*257 + k] - 0.5f;     // rev
        mag  = ini;
        gd   = (float)k * (1.f/512.f);                    // rev per frame
        cs   = (k == 0 ? 1.f : 2.f) * inv;
    }
    // thread 255 additionally owns the Nyquist bin k=256
    const bool has_ny = (tid == 255);
    float res2 = 0.f, dith2 = 0.f, pr2 = 0.f, mag2 = 0.f;
    if (has_ny) {
        float i2 = out3[((size_t)0*1024 + row)*257 + 256];
        float r2 = out3[((size_t)1*1024 + row)*257 + 256];
        float d2 = out3[((size_t)2*1024 + row)*257 + 256];
        res2  = 0.5f + 0.4995f / (1.f + expf(-r2));
        dith2 = 1.f / (1.f + expf(-d2));
        pr2   = phase0_u[(size_t)row*257 + 256] - 0.5f;
        mag2  = i2;
    }

    const float* nrow = noise_u + ((size_t)b*128*512 + e)*257;
    const size_t nstride = (size_t)512*257;

    // OLA constants for col w = tid
    float h1, h2;
    {
        float c0 = __builtin_amdgcn_cosf((float)tid * (1.f/512.f));
        h1 = 0.5f - 0.5f*c0;                        // hann[tid]
        h2 = 0.5f + 0.5f*c0;                        // hann[tid+256]
    }
    const float sgn = (tid & 1) ? -1.f : 1.f;       // (-1)^tid for Nyquist add
    float tail = 0.f;

    const int l  = tid & 63;
    const int wv = tid >> 6;                        // 0..3: 64-col slice
    const int m0 = l & 15;
    const int ac = l >> 4;
    const int4* abt4 = (const int4*)lds_raw;        // row stride 65 int4
    const int4* Tp   = (const int4*)tpack;

    for (int sweep = 0; sweep < 2; ++sweep) {
        const int F0 = sweep * 64;

        // ---- phase 1: scan 64 frames -> abt (+ a256s), 8 frames/round ----
        for (int grp = 0; grp < 8; ++grp) {
            // cooperative staging: wave wv loads frames {2wv, 2wv+1} of round
            #pragma unroll
            for (int fi = 0; fi < 2; ++fi) {
                const int fl = wv*2 + fi;
                const int t  = F0 + grp*8 + fl;
                const float* pf = nrow + (size_t)t*nstride;
                f32x4u v = __builtin_nontemporal_load(((const f32x4u*)pf) + l);
                *(f32x4u*)&nbuf[fl][l*4] = v;
                if (l == 0)
                    nbuf[fl][256] = __builtin_nontemporal_load(pf + 256);
            }
            __syncthreads();

            #pragma unroll
            for (int j = 0; j < 8; ++j) {
                int t = F0 + grp*8 + j;
                if (t >= 1) {
                    mag *= res;
                    pr  += gd + dith * (nbuf[j][k] - 0.5f);
                }
                float fr = pr - floorf(pr);
                float sn = __builtin_amdgcn_sinf(fr);
                float cn = __builtin_amdgcn_cosf(fr);
                float am = cs * mag;
                abt[(grp*8 + j)*260 + k] =
                    (unsigned int)f2bf(am*cn) | ((unsigned int)f2bf(-am*sn) << 16);
                if (has_ny) {
                    if (t >= 1) {
                        mag2 *= res2;
                        pr2  += 0.5f + dith2 * (nbuf[j][256] - 0.5f);
                    }
                    float fr2 = pr2 - floorf(pr2);
                    a256s[grp*8 + j] = inv * mag2 * __builtin_amdgcn_cosf(fr2);
                }
            }
            __syncthreads();   // nbuf/abt round done before next overwrite
        }

        // ---- phase 2: MFMA  M=64 (frames), N=256 (w), K=512; dual-sign ----
        f32x4 accL[4][4], accR[4][4];
        #pragma unroll
        for (int mt = 0; mt < 4; ++mt)
            #pragma unroll
            for (int nt = 0; nt < 4; ++nt) {
                accL[mt][nt] = (f32x4){0.f, 0.f, 0.f, 0.f};
                accR[mt][nt] = (f32x4){0.f, 0.f, 0.f, 0.f};
            }

        {
            const int r0 = m0*65 + ac;
            for (int ks = 0; ks < 16; ++ks) {
                const int4* tb = Tp + (size_t)((ks*16 + wv*4) << 6) + l;
                int4 b0 = tb[0];
                int4 b1 = tb[64];
                int4 b2 = tb[128];
                int4 b3 = tb[192];
                bf16x8 B0 = *(bf16x8*)&b0;
                bf16x8 B1 = *(bf16x8*)&b1;
                bf16x8 B2 = *(bf16x8*)&b2;
                bf16x8 B3 = *(bf16x8*)&b3;
                #pragma unroll
                for (int mt = 0; mt < 4; ++mt) {
                    int4 a = abt4[r0 + mt*(16*65) + ks*4];
                    bf16x8 A = *(bf16x8*)&a;
                    accL[mt][0] = __builtin_amdgcn_mfma_f32_16x16x32_bf16(A, B0, accL[mt][0], 0, 0, 0);
                    accL[mt][1] = __builtin_amdgcn_mfma_f32_16x16x32_bf16(A, B1, accL[mt][1], 0, 0, 0);
                    accL[mt][2] = __builtin_amdgcn_mfma_f32_16x16x32_bf16(A, B2, accL[mt][2], 0, 0, 0);
                    accL[mt][3] = __builtin_amdgcn_mfma_f32_16x16x32_bf16(A, B3, accL[mt][3], 0, 0, 0);
                    int4 a2 = a;
                    a2.y ^= 0x80008000;               // flip sign where k odd
                    a2.w ^= 0x80008000;
                    bf16x8 A2 = *(bf16x8*)&a2;
                    accR[mt][0] = __builtin_amdgcn_mfma_f32_16x16x32_bf16(A2, B0, accR[mt][0], 0, 0, 0);
                    accR[mt][1] = __builtin_amdgcn_mfma_f32_16x16x32_bf16(A2, B1, accR[mt][1], 0, 0, 0);
                    accR[mt][2] = __builtin_amdgcn_mfma_f32_16x16x32_bf16(A2, B2, accR[mt][2], 0, 0, 0);
                    accR[mt][3] = __builtin_amdgcn_mfma_f32_16x16x32_bf16(A2, B3, accR[mt][3], 0, 0, 0);
                }
            }
        }
        __syncthreads();   // abt reads done; xbf may overwrite

        // ---- phase 3: two 32-frame halves: acc -> xbf -> Hann+OLA ----
        #pragma unroll
        for (int h = 0; h < 2; ++h) {
            #pragma unroll
            for (int mt2 = 0; mt2 < 2; ++mt2) {
                int mtg = 2*h + mt2;
                #pragma unroll
                for (int nt = 0; nt < 4; ++nt) {
                    int colL = wv*64 + nt*16 + m0;
                    #pragma unroll
                    for (int r = 0; r < 4; ++r) {
                        int f_loc = mt2*16 + ac*4 + r;
                        xbf[f_loc*516 + colL      ] = accL[mtg][nt][r];
                        xbf[f_loc*516 + colL + 256] = accR[mtg][nt][r];
                    }
                }
            }
            __syncthreads();
            {
                float* orow = out + (size_t)row*32768 + (size_t)(F0 + h*32)*256 + tid;
                #pragma unroll
                for (int f = 0; f < 32; ++f) {
                    float s  = a256s[h*32 + f] * sgn;
                    float x1 = xbf[f*516 + tid] + s;
                    float x2 = xbf[f*516 + tid + 256] + s;
                    float v  = fmaf(x1, h1, tail);
                    tail = x2 * h2;
                    __builtin_nontemporal_store(v, &orow[f*256]);
                }
            }
            __syncthreads();   // xbf reads done before next write / next abt
        }
    }
}

// ------------------------------------------------------------------

extern "C" void kernel_launch(void* const* d_in, const int* in_sizes, int n_in,
                              void* d_out, int out_size, void* d_ws, size_t ws_size,
                              hipStream_t stream)
{
    const float* latents  = (const float*)d_in[0];
    const float* phase0_u = (const float*)d_in[1];
    const float* noise_u  = (const float*)d_in[2];
    const float* Win      = (const float*)d_in[3];
    const float* b_in     = (const float*)d_in[4];
    const float* Wh       = (const float*)d_in[5];
    const float* b_h      = (const float*)d_in[6];
    const float* Wout     = (const float*)d_in[7];
    const float* b_out    = (const float*)d_in[8];

    unsigned char* ws = (unsigned char*)d_ws;
    float*          out3  = (float*)(ws + OUT3_OFF);
    unsigned short* tpack = (unsigned short*)(ws + TPACK_OFF);
    float*          out   = (float*)d_out;

    dim3 gA(128, 3);
    mlp_kernel<<<gA, 256, 0, stream>>>(latents, Win, b_in, Wh, b_h, Wout, b_out, out3);
    tpack_init<<<64, 256, 0, stream>>>(tpack);
    synth_row<<<1024, 256, 0, stream>>>(out3, phase0_u, noise_u, tpack, out);
}

// Round 12
// 227.090 us; speedup vs baseline: 1.8148x; 1.4587x over previous
//
#include <hip/hip_runtime.h>
#include <hip/hip_bf16.h>

#define PI_F 3.14159265358979323846f

typedef short  bf16x8 __attribute__((ext_vector_type(8)));
typedef unsigned short u16x8 __attribute__((ext_vector_type(8)));
typedef float  f32x4  __attribute__((ext_vector_type(4)));

// ---- ws layout (bytes) ----
#define OUT3_OFF  0                       // [3][1024][257] f32 = 3,158,016 B
#define TPACK_OFF 3158016                 // [128 tiles][64][8] bf16 = 131,072 B

#define RPB 8                             // rows per block in mlp_kernel

static __device__ __forceinline__ unsigned short f2bf(float x) {
    unsigned int u = __float_as_uint(x);
    unsigned int r = (u + 0x7fffu + ((u >> 16) & 1u)) >> 16;   // RNE
    return (unsigned short)r;
}

// ------------------------------------------------------------------
// Kernel A: three LinearOutputStacks. 8 rows/block, grid (128,3).
// ------------------------------------------------------------------

__device__ __forceinline__ void block_ln8(float (*buf)[256], float* mrow, float* rrow)
{
    const int tid = threadIdx.x;
    const int lane = tid & 63, wv = tid >> 6;
    for (int r = wv; r < RPB; r += 4) {
        float s = 0.f, s2 = 0.f;
        #pragma unroll
        for (int j = 0; j < 4; j++) {
            float v = buf[r][lane + 64*j];
            s += v; s2 += v*v;
        }
        #pragma unroll
        for (int o = 32; o > 0; o >>= 1) {
            s  += __shfl_xor(s,  o, 64);
            s2 += __shfl_xor(s2, o, 64);
        }
        if (lane == 0) {
            float m   = s * (1.f/256.f);
            float var = s2 * (1.f/256.f) - m*m;
            mrow[r] = m;
            rrow[r] = rsqrtf(var + 1e-5f);
        }
    }
    __syncthreads();
    #pragma unroll
    for (int r = 0; r < RPB; r++)
        buf[r][tid] = (buf[r][tid] - mrow[r]) * rrow[r];
    __syncthreads();
}

// KDIM -> 256 matmul + bias + leaky_relu(0.2)
template<int KDIM>
__device__ __forceinline__ void mmv(const float (*in)[KDIM == 128 ? 128 : 256],
                                    const float* __restrict__ W, int wstride,
                                    const float* __restrict__ bias, float (*outb)[256])
{
    const int tid = threadIdx.x;
    float acc[RPB];
    #pragma unroll
    for (int r = 0; r < RPB; r++) acc[r] = 0.f;
    const float* Wp = W + tid;
    for (int l16 = 0; l16 < KDIM; l16 += 16) {
        float wbuf[16];
        #pragma unroll
        for (int j = 0; j < 16; j++) wbuf[j] = Wp[(size_t)(l16 + j)*wstride];
        #pragma unroll
        for (int q = 0; q < 4; q++) {
            f32x4 iq[RPB];
            #pragma unroll
            for (int r = 0; r < RPB; r++) iq[r] = *(const f32x4*)&in[r][l16 + q*4];
            #pragma unroll
            for (int jj = 0; jj < 4; jj++)
                #pragma unroll
                for (int r = 0; r < RPB; r++)
                    acc[r] = fmaf(iq[r][jj], wbuf[q*4 + jj], acc[r]);
        }
    }
    const float bb = bias[tid];
    #pragma unroll
    for (int r = 0; r < RPB; r++) {
        float v = acc[r] + bb;
        outb[r][tid] = (v >= 0.f) ? v : 0.2f*v;
    }
}

__global__ __launch_bounds__(256) void mlp_kernel(
    const float* __restrict__ latents,
    const float* __restrict__ Win,  const float* __restrict__ b_in,
    const float* __restrict__ Wh,   const float* __restrict__ b_h,
    const float* __restrict__ Wout, const float* __restrict__ b_out,
    float* __restrict__ out3)
{
    __shared__ float bufA[RPB][128];
    __shared__ float bufB[RPB][256];
    __shared__ float bufC[RPB][256];
    __shared__ float mrow[RPB], rrow[RPB];

    const int tid  = threadIdx.x;
    const int s    = blockIdx.y;
    const int row0 = blockIdx.x * RPB;

    for (int idx = tid; idx < RPB*128; idx += 256) {
        int r = idx >> 7, l = idx & 127;
        bufA[r][l] = latents[(size_t)(row0 + r)*128 + l];
    }
    __syncthreads();

    mmv<128>(bufA, Win + (size_t)s*128*256, 256, b_in + s*256, bufB);
    __syncthreads();
    block_ln8(bufB, mrow, rrow);

    mmv<256>(bufB, Wh + ((size_t)s*2 + 0)*256*256, 256, b_h + (s*2 + 0)*256, bufC);
    __syncthreads();
    block_ln8(bufC, mrow, rrow);

    mmv<256>(bufC, Wh + ((size_t)s*2 + 1)*256*256, 256, b_h + (s*2 + 1)*256, bufB);
    __syncthreads();
    block_ln8(bufB, mrow, rrow);

    // output layer: 256 -> 257 (+bias), raw
    for (int pass = 0; pass < 2; ++pass) {
        int n = tid + pass*256;
        if (n < 257) {
            float acc[RPB];
            #pragma unroll
            for (int r = 0; r < RPB; r++) acc[r] = 0.f;
            const float* Wp = Wout + (size_t)s*256*257 + n;
            for (int l16 = 0; l16 < 256; l16 += 16) {
                float wbuf[16];
                #pragma unroll
                for (int j = 0; j < 16; j++) wbuf[j] = Wp[(size_t)(l16 + j)*257];
                #pragma unroll
                for (int q = 0; q < 4; q++) {
                    f32x4 iq[RPB];
                    #pragma unroll
                    for (int r = 0; r < RPB; r++) iq[r] = *(const f32x4*)&bufB[r][l16 + q*4];
                    #pragma unroll
                    for (int jj = 0; jj < 4; jj++)
                        #pragma unroll
                        for (int r = 0; r < RPB; r++)
                            acc[r] = fmaf(iq[r][jj], wbuf[q*4 + jj], acc[r]);
                }
            }
            float bb = b_out[s*257 + n];
            for (int r = 0; r < RPB; r++)
                out3[((size_t)s*1024 + row0 + r)*257 + n] = acc[r] + bb;
        }
    }
}

// ------------------------------------------------------------------
// K1: pack the half-spectrum iDFT basis (k-mirror + w-parity split).
// kappa = k2/2 + 1 in [1,128];  row k2 even -> cos(2pi kappa w/512),
// odd -> sin.  tile = ks*16 + wg*2 + p, lane l elem j:
//   k2 = ks*32 + (l>>4)*8 + j,  w = wg*32 + 2*(l&15) + p.
// 128 tiles x 1 KB = 128 KB.
// ------------------------------------------------------------------
__global__ __launch_bounds__(256) void tpack_init(unsigned short* __restrict__ tp)
{
    int g = blockIdx.x * 256 + threadIdx.x;      // 128*64 = 8192 threads exactly
    int tile = g >> 6, l = g & 63;
    int ks = tile >> 4;                          // 0..7
    int wg = (tile >> 1) & 7;                    // 0..7
    int p  = tile & 1;                           // parity
    u16x8 v;
    #pragma unroll
    for (int j = 0; j < 8; ++j) {
        int k2 = ks*32 + ((l >> 4) << 3) + j;    // < 256
        int kap = (k2 >> 1) + 1;                 // 1..128
        int w  = wg*32 + 2*(l & 15) + p;         // < 256
        int m  = (kap * w) & 511;                // exact angle reduction
        float ang = (float)m * (PI_F / 256.f);
        float sn, cn; sincosf(ang, &sn, &cn);
        v[j] = f2bf((k2 & 1) ? sn : cn);
    }
    *(u16x8*)(tp + (size_t)g * 8) = v;
}

// ------------------------------------------------------------------
// K2: full-row fused scan + half-K MFMA iDFT + Hann/OLA.
// grid 1024, block 512 (8 waves), __launch_bounds__(512,4): 2 blocks/CU.
//   x[w]      = a0 + P(w) + (-1)^w (Q(w) + a256)
//   x[w+256]  = a0 + Pf(w) + (-1)^w (Qf(w) + a256)     (f = odd-kappa flip)
// P over abtP (k=1..128), Q over abtQ (k=129..255 stored at kappa=256-k,
// with b negated).  Even/odd w columns use separate B tiles so the (-1)^w
// factor folds into the A-operand sign (no extra accumulators).
// LDS union: abtP[64][132] + abtQ[64][132] u32  |  xbf f32[32][516].
// ------------------------------------------------------------------
__global__ __launch_bounds__(512, 4) void synth_row(
    const float* __restrict__ out3,
    const float* __restrict__ phase0_u,
    const float* __restrict__ noise_u,
    const unsigned short* __restrict__ tpack,
    float* __restrict__ out)
{
    __shared__ __align__(16) unsigned int lds_u[16896];   // 67,584 B union
    __shared__ float a0s[64];
    __shared__ float a256s[64];

    unsigned int* abtP = lds_u;                  // [64][132] u32
    unsigned int* abtQ = lds_u + 64*132;         // [64][132] u32
    float*        xbf  = (float*)lds_u;          // [32][516] f32

    const int tid = threadIdx.x;
    const int row = blockIdx.x;
    const int b   = row >> 9;
    const int e   = row & 511;

    const float inv = 0.04419417382415922f;      // 1/sqrt(512)

    // ---- per-thread sequential state (k = tid, 0..256), in revolutions ----
    float res = 0.f, dith = 0.f, pr = 0.f, mag = 0.f, gd = 0.f, cs = 0.f;
    unsigned int* tgt = abtP;                    // safe default
    float bsgn = -1.f;                           // P: b = -cs*mag*sin
    if (tid <= 256) {
        const int k = tid;
        float ini  = out3[((size_t)0*1024 + row)*257 + k];
        float rpre = out3[((size_t)1*1024 + row)*257 + k];
        float dpre = out3[((size_t)2*1024 + row)*257 + k];
        res  = 0.5f + 0.4995f / (1.f + expf(-rpre));
        dith = 1.f / (1.f + expf(-dpre));
        pr   = phase0_u[(size_t)row*257 + k] - 0.5f;      // rev
        mag  = ini;
        gd   = (float)k * (1.f/512.f);                     // rev per frame
        cs   = ((k == 0) | (k == 256) ? 1.f : 2.f) * inv;
        if (k >= 129 && k <= 255) { tgt = abtQ + (255 - k); bsgn = 1.f; }
        else if (k >= 1 && k <= 128) { tgt = abtP + (k - 1); }
    }

    const float* nrow = noise_u + ((size_t)b*128*512 + e)*257;
    const size_t nstride = (size_t)512*257;

    // OLA constants for col w = tid (threads < 256)
    float h1 = 0.f, h2 = 0.f;
    {
        float c0 = __builtin_amdgcn_cosf((float)tid * (1.f/512.f));
        h1 = 0.5f - 0.5f*c0;                     // hann[tid]
        h2 = 0.5f + 0.5f*c0;                     // hann[tid+256]
    }
    const float sgn = (tid & 1) ? -1.f : 1.f;    // (-1)^w
    float tail = 0.f;

    const int l  = tid & 63;
    const int wv = tid >> 6;                     // 0..7: 32-col slice
    const int m0 = l & 15;
    const int ac = l >> 4;
    const int4* abtP4 = (const int4*)abtP;       // row stride 33 int4
    const int4* abtQ4 = (const int4*)abtQ;
    const int4* Tp    = (const int4*)tpack;
    const unsigned int S = 0x80008000u;

    for (int sweep = 0; sweep < 2; ++sweep) {
        const int F0 = sweep * 64;

        // ---- phase 1: scan 64 frames -> abtP/abtQ (+ a0s, a256s) ----
        if (tid <= 256) {
            for (int grp = 0; grp < 8; ++grp) {
                float nzb[8];
                #pragma unroll
                for (int j = 0; j < 8; ++j) {
                    int t = F0 + grp*8 + j;
                    nzb[j] = (t >= 1) ? __builtin_nontemporal_load(
                                            &nrow[(size_t)t*nstride + tid]) : 0.5f;
                }
                #pragma unroll
                for (int j = 0; j < 8; ++j) {
                    int t = F0 + grp*8 + j;
                    if (t >= 1) {
                        mag *= res;
                        pr  += gd + dith * (nzb[j] - 0.5f);
                    }
                    float fr = pr - floorf(pr);
                    float sn = __builtin_amdgcn_sinf(fr);
                    float cn = __builtin_amdgcn_cosf(fr);
                    float am = cs * mag;
                    float av = am * cn;
                    if (tid == 0)        a0s[grp*8 + j]   = av;
                    else if (tid == 256) a256s[grp*8 + j] = av;
                    else {
                        float bv = bsgn * am * sn;
                        tgt[(grp*8 + j)*132] =
                            (unsigned int)f2bf(av) | ((unsigned int)f2bf(bv) << 16);
                    }
                }
            }
        } else if (tid >= 448) {
            // zero abtQ kappa=128 column (clobbered by xbf each sweep)
            abtQ[(tid - 448)*132 + 127] = 0;
        }
        __syncthreads();

        // ---- phase 2: MFMA  M=64, N=256 (parity-split), K=256 ----
        f32x4 accE[4], accO[4], accER[4], accOR[4];
        #pragma unroll
        for (int mt = 0; mt < 4; ++mt) {
            accE[mt]  = (f32x4){0.f, 0.f, 0.f, 0.f};
            accO[mt]  = (f32x4){0.f, 0.f, 0.f, 0.f};
            accER[mt] = (f32x4){0.f, 0.f, 0.f, 0.f};
            accOR[mt] = (f32x4){0.f, 0.f, 0.f, 0.f};
        }
        {
            const int r0 = m0*33 + ac;
            for (int ks = 0; ks < 8; ++ks) {
                const int4* tb = Tp + (size_t)((ks*16 + wv*2) << 6) + l;
                int4 be = tb[0];
                int4 bo = tb[64];
                bf16x8 BE = *(bf16x8*)&be;
                bf16x8 BO = *(bf16x8*)&bo;
                #pragma unroll
                for (int mt = 0; mt < 4; ++mt) {
                    int4 ap = abtP4[r0 + mt*528 + ks*4];
                    int4 aq = abtQ4[r0 + mt*528 + ks*4];
                    int4 apf = ap;  apf.x ^= S;  apf.z ^= S;      // flip odd kappa
                    int4 aqf = aq;  aqf.x ^= S;  aqf.z ^= S;
                    int4 aqn = aq;  aqn.x ^= S;  aqn.y ^= S;  aqn.z ^= S;  aqn.w ^= S;
                    int4 aqnf = aq; aqnf.y ^= S; aqnf.w ^= S;     // negate(flip)
                    bf16x8 AP   = *(bf16x8*)&ap;
                    bf16x8 APF  = *(bf16x8*)&apf;
                    bf16x8 AQ   = *(bf16x8*)&aq;
                    bf16x8 AQF  = *(bf16x8*)&aqf;
                    bf16x8 AQN  = *(bf16x8*)&aqn;
                    bf16x8 AQNF = *(bf16x8*)&aqnf;
                    accE[mt]  = __builtin_amdgcn_mfma_f32_16x16x32_bf16(AP,   BE, accE[mt],  0, 0, 0);
                    accE[mt]  = __builtin_amdgcn_mfma_f32_16x16x32_bf16(AQ,   BE, accE[mt],  0, 0, 0);
                    accO[mt]  = __builtin_amdgcn_mfma_f32_16x16x32_bf16(AP,   BO, accO[mt],  0, 0, 0);
                    accO[mt]  = __builtin_amdgcn_mfma_f32_16x16x32_bf16(AQN,  BO, accO[mt],  0, 0, 0);
                    accER[mt] = __builtin_amdgcn_mfma_f32_16x16x32_bf16(APF,  BE, accER[mt], 0, 0, 0);
                    accER[mt] = __builtin_amdgcn_mfma_f32_16x16x32_bf16(AQF,  BE, accER[mt], 0, 0, 0);
                    accOR[mt] = __builtin_amdgcn_mfma_f32_16x16x32_bf16(APF,  BO, accOR[mt], 0, 0, 0);
                    accOR[mt] = __builtin_amdgcn_mfma_f32_16x16x32_bf16(AQNF, BO, accOR[mt], 0, 0, 0);
                }
            }
        }
        __syncthreads();   // abt reads done; xbf may overwrite

        // ---- phase 3: two 32-frame halves: acc -> xbf -> Hann+OLA ----
        #pragma unroll
        for (int h = 0; h < 2; ++h) {
            #pragma unroll
            for (int mt2 = 0; mt2 < 2; ++mt2) {
                int mtg = 2*h + mt2;
                int colE = wv*32 + 2*m0;
                #pragma unroll
                for (int r = 0; r < 4; ++r) {
                    int f_loc = mt2*16 + ac*4 + r;
                    float2 vL = make_float2(accE[mtg][r],  accO[mtg][r]);
                    float2 vR = make_float2(accER[mtg][r], accOR[mtg][r]);
                    *(float2*)&xbf[f_loc*516 + colE      ] = vL;
                    *(float2*)&xbf[f_loc*516 + colE + 256] = vR;
                }
            }
            __syncthreads();
            if (tid < 256) {
                float* orow = out + (size_t)row*32768 + (size_t)(F0 + h*32)*256 + tid;
                #pragma unroll
                for (int f = 0; f < 32; ++f) {
                    int hf = h*32 + f;
                    float s  = a0s[hf] + sgn * a256s[hf];
                    float x1 = xbf[f*516 + tid] + s;
                    float x2 = xbf[f*516 + tid + 256] + s;
                    float v  = fmaf(x1, h1, tail);
                    tail = x2 * h2;
                    __builtin_nontemporal_store(v, &orow[f*256]);
                }
            }
            __syncthreads();   // xbf reads done before next write / next abt
        }
    }
}

// ------------------------------------------------------------------

extern "C" void kernel_launch(void* const* d_in, const int* in_sizes, int n_in,
                              void* d_out, int out_size, void* d_ws, size_t ws_size,
                              hipStream_t stream)
{
    const float* latents  = (const float*)d_in[0];
    const float* phase0_u = (const float*)d_in[1];
    const float* noise_u  = (const float*)d_in[2];
    const float* Win      = (const float*)d_in[3];
    const float* b_in     = (const float*)d_in[4];
    const float* Wh       = (const float*)d_in[5];
    const float* b_h      = (const float*)d_in[6];
    const float* Wout     = (const float*)d_in[7];
    const float* b_out    = (const float*)d_in[8];

    unsigned char* ws = (unsigned char*)d_ws;
    float*          out3  = (float*)(ws + OUT3_OFF);
    unsigned short* tpack = (unsigned short*)(ws + TPACK_OFF);
    float*          out   = (float*)d_out;

    dim3 gA(128, 3);
    mlp_kernel<<<gA, 256, 0, stream>>>(latents, Win, b_in, Wh, b_h, Wout, b_out, out3);
    tpack_init<<<32, 256, 0, stream>>>(tpack);
    synth_row<<<1024, 512, 0, stream>>>(out3, phase0_u, noise_u, tpack, out);
}

// Round 13
// 219.370 us; speedup vs baseline: 1.8787x; 1.0352x over previous
//
#include <hip/hip_runtime.h>
#include <hip/hip_bf16.h>

#define PI_F 3.14159265358979323846f

typedef short  bf16x8 __attribute__((ext_vector_type(8)));
typedef unsigned short u16x8 __attribute__((ext_vector_type(8)));
typedef float  f32x4  __attribute__((ext_vector_type(4)));

// ---- ws layout (bytes) ----
#define OUT3_OFF  0                       // [3][1024][257] f32 = 3,158,016 B
#define TPACK_OFF 3158016                 // [128 tiles][64][8] bf16 = 131,072 B

static __device__ __forceinline__ unsigned short f2bf(float x) {
    unsigned int u = __float_as_uint(x);
    unsigned int r = (u + 0x7fffu + ((u >> 16) & 1u)) >> 16;   // RNE
    return (unsigned short)r;
}

static __device__ __forceinline__ float sigm(float x) {
    return 1.f / (1.f + expf(-x));
}

// ------------------------------------------------------------------
// Kernel A: three LinearOutputStacks. 8 rows/block, 512 threads,
// row-half split (rows 0-3 / 4-7). grid (128,3) = 384 blocks, 8 waves each.
// ------------------------------------------------------------------

__device__ __forceinline__ void ln512(float (*buf)[256], float* mrow, float* rrow)
{
    const int tid = threadIdx.x;
    const int lane = tid & 63, wv = tid >> 6;      // wave wv reduces row wv
    float s = 0.f, s2 = 0.f;
    #pragma unroll
    for (int j = 0; j < 4; j++) {
        float v = buf[wv][lane + 64*j];
        s += v; s2 += v*v;
    }
    #pragma unroll
    for (int o = 32; o > 0; o >>= 1) {
        s  += __shfl_xor(s,  o, 64);
        s2 += __shfl_xor(s2, o, 64);
    }
    if (lane == 0) {
        float m   = s * (1.f/256.f);
        float var = s2 * (1.f/256.f) - m*m;
        mrow[wv] = m;
        rrow[wv] = rsqrtf(var + 1e-5f);
    }
    __syncthreads();
    #pragma unroll
    for (int idx = tid; idx < 2048; idx += 512) {
        int r = idx >> 8, cc = idx & 255;
        buf[r][cc] = (buf[r][cc] - mrow[r]) * rrow[r];
    }
    __syncthreads();
}

// KDIM -> 256 matmul + bias + leaky_relu(0.2), row-half split
template<int KDIM>
__device__ __forceinline__ void mmvh(const float (*in)[KDIM],
                                     const float* __restrict__ W,
                                     const float* __restrict__ bias,
                                     float (*outb)[256])
{
    const int tid = threadIdx.x;
    const int c  = tid & 255;
    const int r0 = (tid >> 8) * 4;
    float acc[4] = {0.f, 0.f, 0.f, 0.f};
    const float* Wp = W + c;
    for (int l16 = 0; l16 < KDIM; l16 += 16) {
        float wbuf[16];
        #pragma unroll
        for (int j = 0; j < 16; j++) wbuf[j] = Wp[(size_t)(l16 + j)*256];
        #pragma unroll
        for (int q = 0; q < 4; q++) {
            f32x4 iq[4];
            #pragma unroll
            for (int r = 0; r < 4; r++) iq[r] = *(const f32x4*)&in[r0 + r][l16 + q*4];
            #pragma unroll
            for (int jj = 0; jj < 4; jj++)
                #pragma unroll
                for (int r = 0; r < 4; r++)
                    acc[r] = fmaf(iq[r][jj], wbuf[q*4 + jj], acc[r]);
        }
    }
    const float bb = bias[c];
    #pragma unroll
    for (int r = 0; r < 4; r++) {
        float v = acc[r] + bb;
        outb[r0 + r][c] = (v >= 0.f) ? v : 0.2f*v;
    }
}

__global__ __launch_bounds__(512) void mlp_kernel(
    const float* __restrict__ latents,
    const float* __restrict__ Win,  const float* __restrict__ b_in,
    const float* __restrict__ Wh,   const float* __restrict__ b_h,
    const float* __restrict__ Wout, const float* __restrict__ b_out,
    float* __restrict__ out3)
{
    __shared__ float bufA[8][128];
    __shared__ float bufB[8][256];
    __shared__ float bufC[8][256];
    __shared__ float mrow[8], rrow[8];

    const int tid  = threadIdx.x;
    const int s    = blockIdx.y;
    const int row0 = blockIdx.x * 8;
    const int c    = tid & 255;
    const int r0   = (tid >> 8) * 4;

    for (int idx = tid; idx < 8*128; idx += 512) {
        int r = idx >> 7, l = idx & 127;
        bufA[r][l] = latents[(size_t)(row0 + r)*128 + l];
    }
    __syncthreads();

    mmvh<128>(bufA, Win + (size_t)s*128*256, b_in + s*256, bufB);
    __syncthreads();
    ln512(bufB, mrow, rrow);

    mmvh<256>(bufB, Wh + ((size_t)s*2 + 0)*256*256, b_h + (s*2 + 0)*256, bufC);
    __syncthreads();
    ln512(bufC, mrow, rrow);

    mmvh<256>(bufC, Wh + ((size_t)s*2 + 1)*256*256, b_h + (s*2 + 1)*256, bufB);
    __syncthreads();
    ln512(bufB, mrow, rrow);

    // output layer: 256 -> 257 (+bias), raw
    {
        float acc[4] = {0.f, 0.f, 0.f, 0.f};
        const float* Wp = Wout + (size_t)s*256*257 + c;
        for (int l16 = 0; l16 < 256; l16 += 16) {
            float wbuf[16];
            #pragma unroll
            for (int j = 0; j < 16; j++) wbuf[j] = Wp[(size_t)(l16 + j)*257];
            #pragma unroll
            for (int q = 0; q < 4; q++) {
                f32x4 iq[4];
                #pragma unroll
                for (int r = 0; r < 4; r++) iq[r] = *(const f32x4*)&bufB[r0 + r][l16 + q*4];
                #pragma unroll
                for (int jj = 0; jj < 4; jj++)
                    #pragma unroll
                    for (int r = 0; r < 4; r++)
                        acc[r] = fmaf(iq[r][jj], wbuf[q*4 + jj], acc[r]);
            }
        }
        float bb = b_out[s*257 + c];
        #pragma unroll
        for (int r = 0; r < 4; r++)
            out3[((size_t)s*1024 + row0 + r0 + r)*257 + c] = acc[r] + bb;

        // column 256 (one thread per row; overlaps with other waves' stores)
        if (tid < 8) {
            const int r = tid;
            float a = 0.f;
            const float* Wp2 = Wout + (size_t)s*256*257 + 256;
            for (int l = 0; l < 256; ++l)
                a = fmaf(bufB[r][l], Wp2[(size_t)l*257], a);
            out3[((size_t)s*1024 + row0 + r)*257 + 256] = a + b_out[s*257 + 256];
        }
    }
}

// ------------------------------------------------------------------
// K1: pack the half-spectrum iDFT basis (k-mirror + w-parity split).
// kappa = k2/2 + 1 in [1,128];  row k2 even -> cos(2pi kappa w/512),
// odd -> sin.  tile = ks*16 + wg*2 + p;  128 tiles x 1 KB = 128 KB.
// ------------------------------------------------------------------
__global__ __launch_bounds__(256) void tpack_init(unsigned short* __restrict__ tp)
{
    int g = blockIdx.x * 256 + threadIdx.x;      // 128*64 = 8192 threads exactly
    int tile = g >> 6, l = g & 63;
    int ks = tile >> 4;                          // 0..7
    int wg = (tile >> 1) & 7;                    // 0..7
    int p  = tile & 1;                           // parity
    u16x8 v;
    #pragma unroll
    for (int j = 0; j < 8; ++j) {
        int k2 = ks*32 + ((l >> 4) << 3) + j;    // < 256
        int kap = (k2 >> 1) + 1;                 // 1..128
        int w  = wg*32 + 2*(l & 15) + p;         // < 256
        int m  = (kap * w) & 511;                // exact angle reduction
        float ang = (float)m * (PI_F / 256.f);
        float sn, cn; sincosf(ang, &sn, &cn);
        v[j] = f2bf((k2 & 1) ? sn : cn);
    }
    *(u16x8*)(tp + (size_t)g * 8) = v;
}

// ------------------------------------------------------------------
// K2: full-row fused scan + half-K MFMA iDFT + Hann/OLA.
// grid 1024, block 512 (8 waves), __launch_bounds__(512,4): 2 blocks/CU.
// SCAN is producer/consumer split:
//  - producers (tid<=256): sequential phase cumsum only (1 fma/frame),
//    write pr to pbuf[8][260]; thread 256 also evaluates the Nyquist bin.
//  - consumers (ALL 512): evaluate fract/sin/cos/scale/f2bf for
//    (bin = tid&255, frames j0..j0+3, j0 = (tid>>8)*4) per group;
//    magnitude via running products m_base *= res^8 (matches the ref's
//    exp(t*log res) closed form; noise-independent).
// GEMM/epilogue identical to round 12 (parity-split, K=256).
// ------------------------------------------------------------------
__global__ __launch_bounds__(512, 4) void synth_row(
    const float* __restrict__ out3,
    const float* __restrict__ phase0_u,
    const float* __restrict__ noise_u,
    const unsigned short* __restrict__ tpack,
    float* __restrict__ out)
{
    __shared__ __align__(16) unsigned int lds_u[16896];   // 67,584 B union
    __shared__ float a0s[64];
    __shared__ float a256s[64];
    __shared__ float pbuf[8][260];                        // 8,320 B

    unsigned int* abtP = lds_u;                  // [64][132] u32
    unsigned int* abtQ = lds_u + 64*132;         // [64][132] u32
    float*        xbf  = (float*)lds_u;          // [32][516] f32

    const int tid = threadIdx.x;
    const int row = blockIdx.x;
    const int b   = row >> 9;
    const int e   = row & 511;

    const float inv = 0.04419417382415922f;      // 1/sqrt(512)

    // ---- producer init (tid <= 256): phase recurrence only ----
    float pr = 0.f, dith_ = 0.f, gdd = 0.f;
    if (tid <= 256) {
        float dpre = out3[((size_t)2*1024 + row)*257 + tid];
        dith_ = sigm(dpre);
        float gd = (float)tid * (1.f/512.f);
        gdd = gd - 0.5f*dith_;                   // pr += fma(dith, nz, gdd)
        pr  = phase0_u[(size_t)row*257 + tid] - 0.5f;
    }
    // thread 256: full Nyquist-bin evaluation state
    float m2 = 0.f, res2_ = 0.f;
    if (tid == 256) {
        float i2 = out3[((size_t)0*1024 + row)*257 + 256];
        float r2 = out3[((size_t)1*1024 + row)*257 + 256];
        res2_ = 0.5f + 0.4995f * sigm(r2);
        m2    = inv * i2;
    }

    // ---- consumer init (all threads): bin kc, frames j0..j0+3 ----
    const int kc = tid & 255;
    const int j0 = (tid >> 8) * 4;               // 0 or 4
    float m_base, rp1, rp2, rp3, res8;
    float bsgn = -1.f;
    unsigned int* tgt = abtP;                    // kc==0 never writes tgt
    {
        float ini  = out3[((size_t)0*1024 + row)*257 + kc];
        float rpre = out3[((size_t)1*1024 + row)*257 + kc];
        float res  = 0.5f + 0.4995f * sigm(rpre);
        float cs   = (kc == 0 ? 1.f : 2.f) * inv;
        rp1 = res;
        rp2 = res * res;
        rp3 = rp2 * res;
        float res4 = rp2 * rp2;
        res8 = res4 * res4;
        m_base = cs * ini;
        if (j0 == 4) m_base *= res4;
        if (kc >= 129)     { tgt = abtQ + (255 - kc); bsgn = 1.f; }
        else if (kc >= 1)  { tgt = abtP + (kc - 1); }
    }

    const float* nrow = noise_u + ((size_t)b*128*512 + e)*257;
    const size_t nstride = (size_t)512*257;

    // OLA constants for col w = tid (threads < 256)
    float h1 = 0.f, h2 = 0.f;
    {
        float c0 = __builtin_amdgcn_cosf((float)tid * (1.f/512.f));
        h1 = 0.5f - 0.5f*c0;                     // hann[tid]
        h2 = 0.5f + 0.5f*c0;                     // hann[tid+256]
    }
    const float sgn = (tid & 1) ? -1.f : 1.f;    // (-1)^w
    float tail = 0.f;

    const int l  = tid & 63;
    const int wv = tid >> 6;                     // 0..7: 32-col slice
    const int m0 = l & 15;
    const int ac = l >> 4;
    const int4* abtP4 = (const int4*)abtP;       // row stride 33 int4
    const int4* abtQ4 = (const int4*)abtQ;
    const int4* Tp    = (const int4*)tpack;
    const unsigned int S = 0x80008000u;

    for (int sweep = 0; sweep < 2; ++sweep) {
        const int F0 = sweep * 64;

        // ---- phase 1: producer/consumer scan, 8 groups of 8 frames ----
        for (int g = 0; g < 8; ++g) {
            if (tid <= 256) {
                float nzb[8];
                #pragma unroll
                for (int j = 0; j < 8; ++j) {
                    int t = F0 + g*8 + j;
                    nzb[j] = (t >= 1) ? __builtin_nontemporal_load(
                                            &nrow[(size_t)t*nstride + tid]) : 0.5f;
                }
                #pragma unroll
                for (int j = 0; j < 8; ++j) {
                    int t = F0 + g*8 + j;
                    if (t >= 1) pr += fmaf(dith_, nzb[j], gdd);
                    pbuf[j][tid] = pr;
                    if (tid == 256) {            // Nyquist: cos only
                        if (t >= 1) m2 *= res2_;
                        float fr = pr - floorf(pr);
                        a256s[g*8 + j] = m2 * __builtin_amdgcn_cosf(fr);
                    }
                }
            } else if (g == 0 && tid >= 448) {
                // zero abtQ kappa=128 column (clobbered by xbf each sweep)
                abtQ[(tid - 448)*132 + 127] = 0;
            }
            __syncthreads();

            // consumers: all 512 threads, 4 (bin,frame) items each
            {
                const int fb = g*8 + j0;
                float mv[4];
                mv[0] = m_base;
                mv[1] = m_base * rp1;
                mv[2] = m_base * rp2;
                mv[3] = m_base * rp3;
                #pragma unroll
                for (int q = 0; q < 4; ++q) {
                    float p  = pbuf[j0 + q][kc];
                    float fr = p - floorf(p);
                    float sn = __builtin_amdgcn_sinf(fr);
                    float cn = __builtin_amdgcn_cosf(fr);
                    float a  = mv[q] * cn;
                    if (kc == 0) {
                        a0s[fb + q] = a;
                    } else {
                        float bv = bsgn * mv[q] * sn;
                        tgt[(fb + q)*132] =
                            (unsigned int)f2bf(a) | ((unsigned int)f2bf(bv) << 16);
                    }
                }
                m_base *= res8;
            }
            __syncthreads();
        }

        // ---- phase 2: MFMA  M=64, N=256 (parity-split), K=256 ----
        f32x4 accE[4], accO[4], accER[4], accOR[4];
        #pragma unroll
        for (int mt = 0; mt < 4; ++mt) {
            accE[mt]  = (f32x4){0.f, 0.f, 0.f, 0.f};
            accO[mt]  = (f32x4){0.f, 0.f, 0.f, 0.f};
            accER[mt] = (f32x4){0.f, 0.f, 0.f, 0.f};
            accOR[mt] = (f32x4){0.f, 0.f, 0.f, 0.f};
        }
        {
            const int r0g = m0*33 + ac;
            for (int ks = 0; ks < 8; ++ks) {
                const int4* tb = Tp + (size_t)((ks*16 + wv*2) << 6) + l;
                int4 be = tb[0];
                int4 bo = tb[64];
                bf16x8 BE = *(bf16x8*)&be;
                bf16x8 BO = *(bf16x8*)&bo;
                #pragma unroll
                for (int mt = 0; mt < 4; ++mt) {
                    int4 ap = abtP4[r0g + mt*528 + ks*4];
                    int4 aq = abtQ4[r0g + mt*528 + ks*4];
                    int4 apf = ap;  apf.x ^= S;  apf.z ^= S;      // flip odd kappa
                    int4 aqf = aq;  aqf.x ^= S;  aqf.z ^= S;
                    int4 aqn = aq;  aqn.x ^= S;  aqn.y ^= S;  aqn.z ^= S;  aqn.w ^= S;
                    int4 aqnf = aq; aqnf.y ^= S; aqnf.w ^= S;     // negate(flip)
                    bf16x8 AP   = *(bf16x8*)&ap;
                    bf16x8 APF  = *(bf16x8*)&apf;
                    bf16x8 AQ   = *(bf16x8*)&aq;
                    bf16x8 AQF  = *(bf16x8*)&aqf;
                    bf16x8 AQN  = *(bf16x8*)&aqn;
                    bf16x8 AQNF = *(bf16x8*)&aqnf;
                    accE[mt]  = __builtin_amdgcn_mfma_f32_16x16x32_bf16(AP,   BE, accE[mt],  0, 0, 0);
                    accE[mt]  = __builtin_amdgcn_mfma_f32_16x16x32_bf16(AQ,   BE, accE[mt],  0, 0, 0);
                    accO[mt]  = __builtin_amdgcn_mfma_f32_16x16x32_bf16(AP,   BO, accO[mt],  0, 0, 0);
                    accO[mt]  = __builtin_amdgcn_mfma_f32_16x16x32_bf16(AQN,  BO, accO[mt],  0, 0, 0);
                    accER[mt] = __builtin_amdgcn_mfma_f32_16x16x32_bf16(APF,  BE, accER[mt], 0, 0, 0);
                    accER[mt] = __builtin_amdgcn_mfma_f32_16x16x32_bf16(AQF,  BE, accER[mt], 0, 0, 0);
                    accOR[mt] = __builtin_amdgcn_mfma_f32_16x16x32_bf16(APF,  BO, accOR[mt], 0, 0, 0);
                    accOR[mt] = __builtin_amdgcn_mfma_f32_16x16x32_bf16(AQNF, BO, accOR[mt], 0, 0, 0);
                }
            }
        }
        __syncthreads();   // abt reads done; xbf may overwrite

        // ---- phase 3: two 32-frame halves: acc -> xbf -> Hann+OLA ----
        #pragma unroll
        for (int h = 0; h < 2; ++h) {
            #pragma unroll
            for (int mt2 = 0; mt2 < 2; ++mt2) {
                int mtg = 2*h + mt2;
                int colE = wv*32 + 2*m0;
                #pragma unroll
                for (int r = 0; r < 4; ++r) {
                    int f_loc = mt2*16 + ac*4 + r;
                    float2 vL = make_float2(accE[mtg][r],  accO[mtg][r]);
                    float2 vR = make_float2(accER[mtg][r], accOR[mtg][r]);
                    *(float2*)&xbf[f_loc*516 + colE      ] = vL;
                    *(float2*)&xbf[f_loc*516 + colE + 256] = vR;
                }
            }
            __syncthreads();
            if (tid < 256) {
                float* orow = out + (size_t)row*32768 + (size_t)(F0 + h*32)*256 + tid;
                #pragma unroll
                for (int f = 0; f < 32; ++f) {
                    int hf = h*32 + f;
                    float s  = a0s[hf] + sgn * a256s[hf];
                    float x1 = xbf[f*516 + tid] + s;
                    float x2 = xbf[f*516 + tid + 256] + s;
                    float v  = fmaf(x1, h1, tail);
                    tail = x2 * h2;
                    __builtin_nontemporal_store(v, &orow[f*256]);
                }
            }
            __syncthreads();   // xbf reads done before next write / next abt
        }
    }
}

// ------------------------------------------------------------------

extern "C" void kernel_launch(void* const* d_in, const int* in_sizes, int n_in,
                              void* d_out, int out_size, void* d_ws, size_t ws_size,
                              hipStream_t stream)
{
    const float* latents  = (const float*)d_in[0];
    const float* phase0_u = (const float*)d_in[1];
    const float* noise_u  = (const float*)d_in[2];
    const float* Win      = (const float*)d_in[3];
    const float* b_in     = (const float*)d_in[4];
    const float* Wh       = (const float*)d_in[5];
    const float* b_h      = (const float*)d_in[6];
    const float* Wout     = (const float*)d_in[7];
    const float* b_out    = (const float*)d_in[8];

    unsigned char* ws = (unsigned char*)d_ws;
    float*          out3  = (float*)(ws + OUT3_OFF);
    unsigned short* tpack = (unsigned short*)(ws + TPACK_OFF);
    float*          out   = (float*)d_out;

    dim3 gA(128, 3);
    mlp_kernel<<<gA, 512, 0, stream>>>(latents, Win, b_in, Wh, b_h, Wout, b_out, out3);
    tpack_init<<<32, 256, 0, stream>>>(tpack);
    synth_row<<<1024, 512, 0, stream>>>(out3, phase0_u, noise_u, tpack, out);
}